// Round 5
// baseline (273.952 us; speedup 1.0000x reference)
//
#include <hip/hip_runtime.h>
#include <hip/hip_bf16.h>

#define BS 16
#define LQ 300
#define DIM 256
#define NH 8
#define HD 32
#define SUMP 16
#define LV 8500
#define NQ (BS*LQ)       // 4800
#define MROWS (BS*LV)    // 136000
#define ES 130           // epilogue C-tile row stride (shorts) = 65 dwords = 1 mod 32 banks

typedef __bf16 bf16x4 __attribute__((ext_vector_type(4)));
typedef __bf16 bf16x8 __attribute__((ext_vector_type(8)));
typedef float f32x4 __attribute__((ext_vector_type(4)));

__device__ __forceinline__ float bf2f(unsigned short u) {
    return __uint_as_float(((unsigned)u) << 16);
}
// 4 fp32 -> 4 bf16 (8B); plain casts so compiler emits v_cvt_pk_bf16_f32
__device__ __forceinline__ bf16x4 cvt8B(float4 a) {
    bf16x4 r;
    r[0] = (__bf16)a.x; r[1] = (__bf16)a.y; r[2] = (__bf16)a.z; r[3] = (__bf16)a.w;
    return r;
}
__device__ __forceinline__ bf16x8 cvt16B(float4 a, float4 b) {
    bf16x8 r;
    r[0] = (__bf16)a.x; r[1] = (__bf16)a.y; r[2] = (__bf16)a.z; r[3] = (__bf16)a.w;
    r[4] = (__bf16)b.x; r[5] = (__bf16)b.y; r[6] = (__bf16)b.z; r[7] = (__bf16)b.w;
    return r;
}

// ---------------- K1: v_bf16 = bf16( value @ W_val^T + b_val ) -----------
// NO main-loop LDS, NO barriers: MFMA fragments are loaded directly from
// global (a frag wave-load = 16 rows x contiguous bytes, coalesced), with
// in-register fp32->bf16 convert. A is prefetched one K-step ahead; B is
// L2-resident (256KB). Waves fully independent -> latency hidden by
// occupancy instead of barrier-coupled pipelining. Block-ID swizzle keeps
// the (bm, bn=0/1) pair on the same XCD (ids congruent mod 8) so the
// second read of each A-row L2-hits. LDS used only for the coalesced
// bf16 epilogue (verified in R3: WRITE_SIZE = ideal).
__global__ __launch_bounds__(256) void k_val_gemm(
    const float* __restrict__ value, const float* __restrict__ Wv,
    const float* __restrict__ bv, unsigned short* __restrict__ vout)
{
    __shared__ unsigned short SH[64 * ES];   // 16.6KB epilogue staging
    const int t = threadIdx.x;
    const int lane = t & 63, wid = t >> 6;
    const int wm = (wid >> 1) * 64, wn = (wid & 1) * 64;
    const int fra = lane & 15;
    const int kg8 = (lane >> 4) * 8;         // k-offset in floats: 0,8,16,24

    // swizzle: id -> (bm, bn) with the two bn-blocks of one bm 8 ids apart
    const int id = blockIdx.x;               // 0..2125
    int bm, bn;
    if (id < 2112) { bm = (id >> 4) * 8 + (id & 7); bn = (id >> 3) & 1; }
    else           { int r = id - 2112; bm = 1056 + (r % 7); bn = r / 7; }

    f32x4 acc[4][4] = {};

    // per-lane row bases (floats)
    unsigned abase[4], bbase[4];
    #pragma unroll
    for (int i = 0; i < 4; ++i) {
        long gr = (long)bm * 128 + wm + i * 16 + fra;
        if (gr > MROWS - 1) gr = MROWS - 1;
        abase[i] = (unsigned)(gr * 256) + kg8;
        bbase[i] = (unsigned)((bn * 128 + wn + i * 16 + fra) * 256) + kg8;
    }

    // prologue: A loads for kt=0
    float4 na0[4], na1[4];
    #pragma unroll
    for (int i = 0; i < 4; ++i) {
        na0[i] = *(const float4*)(value + abase[i]);
        na1[i] = *(const float4*)(value + abase[i] + 4);
    }

    #pragma unroll
    for (int kt = 0; kt < 8; ++kt) {
        const unsigned k0 = kt * 32;
        // issue B loads for current step (L2-hot)
        float4 b0[4], b1[4];
        #pragma unroll
        for (int j = 0; j < 4; ++j) {
            b0[j] = *(const float4*)(Wv + bbase[j] + k0);
            b1[j] = *(const float4*)(Wv + bbase[j] + k0 + 4);
        }
        // convert current A (already in regs)
        bf16x8 af[4];
        #pragma unroll
        for (int i = 0; i < 4; ++i) af[i] = cvt16B(na0[i], na1[i]);
        // prefetch next A
        if (kt < 7) {
            #pragma unroll
            for (int i = 0; i < 4; ++i) {
                na0[i] = *(const float4*)(value + abase[i] + k0 + 32);
                na1[i] = *(const float4*)(value + abase[i] + k0 + 36);
            }
        }
        // convert B, then MFMA
        bf16x8 bfv[4];
        #pragma unroll
        for (int j = 0; j < 4; ++j) bfv[j] = cvt16B(b0[j], b1[j]);
        #pragma unroll
        for (int i = 0; i < 4; ++i)
            #pragma unroll
            for (int j = 0; j < 4; ++j)
                acc[i][j] = __builtin_amdgcn_mfma_f32_16x16x32_bf16(
                    bfv[j], af[i], acc[i][j], 0, 0, 0);  // swapped: lane holds m, 4 consecutive n
    }

    // epilogue in 2 halves of 64 rows; lane holds C[m][n0..n0+3]
    const int nreg = (lane >> 4) * 4;
    #pragma unroll
    for (int half = 0; half < 2; ++half) {
        __syncthreads();
        if ((wm >> 6) == half) {
            #pragma unroll
            for (int j = 0; j < 4; ++j) {
                const float4 bj = *(const float4*)&bv[bn * 128 + wn + j * 16 + nreg];
                #pragma unroll
                for (int i = 0; i < 4; ++i) {
                    const int mloc = i * 16 + fra;            // 0..63
                    const int n0 = wn + j * 16 + nreg;
                    float4 v;
                    v.x = acc[i][j][0] + bj.x;
                    v.y = acc[i][j][1] + bj.y;
                    v.z = acc[i][j][2] + bj.z;
                    v.w = acc[i][j][3] + bj.w;
                    *(bf16x4*)&SH[mloc * ES + n0] = cvt8B(v);
                }
            }
        }
        __syncthreads();
        // copy 64 rows x 128 cols bf16: 4 iters, 16B/thread, coalesced
        #pragma unroll
        for (int u = 0; u < 4; ++u) {
            const int f = u * 256 + t;
            const int row = f >> 4;
            const int col = (f & 15) * 8;
            const long grow = (long)bm * 128 + half * 64 + row;
            if (grow < MROWS)
                *(uint4*)&vout[grow * 256 + bn * 128 + col] = *(const uint4*)&SH[row * ES + col];
        }
    }
}

// ---------------- K2: off/attn projections + softmax + sampling locs ----
__global__ __launch_bounds__(384) void k_offattn(
    const float* __restrict__ query, const float* __restrict__ refp,
    const float* __restrict__ Woff, const float* __restrict__ boff,
    const float* __restrict__ Wattn, const float* __restrict__ battn,
    float* __restrict__ loc, float* __restrict__ aw)
{
    __shared__ float qlds[8][256];
    __shared__ float res[8][384];
    const int t = threadIdx.x;
    const int qg0 = blockIdx.x * 8;

    for (int idx = t; idx < 2048; idx += 384)
        ((float*)qlds)[idx] = query[(long)qg0 * 256 + idx];
    __syncthreads();

    const float* wrow = (t < 256) ? (Woff + (long)t * 256) : (Wattn + (long)(t - 256) * 256);
    float acc[8] = {0.f, 0.f, 0.f, 0.f, 0.f, 0.f, 0.f, 0.f};
    #pragma unroll 4
    for (int k4 = 0; k4 < 64; ++k4) {
        float4 w = *(const float4*)(wrow + k4 * 4);
        #pragma unroll
        for (int q = 0; q < 8; ++q) {
            float4 qv = *(const float4*)&qlds[q][k4 * 4];
            acc[q] += w.x * qv.x + w.y * qv.y + w.z * qv.z + w.w * qv.w;
        }
    }
    const float bias = (t < 256) ? boff[t] : battn[t - 256];
    #pragma unroll
    for (int q = 0; q < 8; ++q) res[q][t] = acc[q] + bias;
    __syncthreads();

    if (t < 64) {
        const int q = t >> 3, h = t & 7;
        const int qg = qg0 + q;
        const float rx = refp[qg * 4 + 0], ry = refp[qg * 4 + 1];
        const float rz = refp[qg * 4 + 2], rw = refp[qg * 4 + 3];
        float m = -1e30f;
        #pragma unroll
        for (int p = 0; p < 16; ++p) m = fmaxf(m, res[q][256 + h * 16 + p]);
        float e[16]; float s = 0.f;
        #pragma unroll
        for (int p = 0; p < 16; ++p) { e[p] = expf(res[q][256 + h * 16 + p] - m); s += e[p]; }
        const float inv = 1.f / s;
        const float sx = 0.25f * rz * 0.5f, sy = 0.25f * rw * 0.5f;
        #pragma unroll
        for (int p = 0; p < 16; ++p) {
            const float ox = res[q][(h * 16 + p) * 2], oy = res[q][(h * 16 + p) * 2 + 1];
            const long base = (long)(qg * 8 + h) * 16 + p;
            loc[base * 2 + 0] = rx + ox * sx;
            loc[base * 2 + 1] = ry + oy * sy;
            aw[base] = e[p] * inv;
        }
    }
}

// ---------------- K3: bilinear sampling + attention-weighted sum ---------
__global__ __launch_bounds__(256) void k_sample(
    const unsigned short* __restrict__ vbf, const float* __restrict__ loc,
    const float* __restrict__ aw, float* __restrict__ sampled)
{
    const int t = threadIdx.x;
    const int wid = t >> 6, lane = t & 63;
    const int id = blockIdx.x * 4 + wid;   // qg*8 + h, 38400 total
    const int h = id & 7;
    const int qg = id >> 3;
    const int b = qg / LQ;
    const int c2 = lane & 31;
    const int half = lane >> 5;

    const unsigned short* vb = vbf + (long)b * LV * 256 + h * 32 + c2;
    const float* locp = loc + (long)id * SUMP * 2;
    const float* awp = aw + (long)id * SUMP;

    const int WLs[4] = {80, 40, 20, 10};
    const int SVs[4] = {0, 6400, 8000, 8400};

    // hoist all loc/aw loads: one latency instead of 8 serial chains
    float lx[8], ly[8], aww[8];
    #pragma unroll
    for (int pp = 0; pp < 8; ++pp) {
        const int p = pp * 2 + half;
        const float2 l2 = *(const float2*)&locp[p * 2];
        lx[pp] = l2.x; ly[pp] = l2.y;
        aww[pp] = awp[p];
    }

    float acc = 0.f;
    #pragma unroll
    for (int pp = 0; pp < 8; ++pp) {
        const int lvl = pp >> 1;               // pair never straddles a level
        const int Wl = WLs[lvl], Hl = WLs[lvl];
        const unsigned short* base = vb + SVs[lvl] * 256;
        const float x = lx[pp] * Wl - 0.5f, y = ly[pp] * Hl - 0.5f;
        const float x0f = floorf(x), y0f = floorf(y);
        const float wx = x - x0f, wy = y - y0f;
        const int x0 = (int)x0f, y0 = (int)y0f;
        #pragma unroll
        for (int dy = 0; dy < 2; ++dy) {
            const int yi = y0 + dy;
            if (yi < 0 || yi >= Hl) continue;
            const float wyv = dy ? wy : 1.f - wy;
            #pragma unroll
            for (int dx = 0; dx < 2; ++dx) {
                const int xi = x0 + dx;
                if (xi < 0 || xi >= Wl) continue;
                const float wxv = dx ? wx : 1.f - wx;
                acc = fmaf(aww[pp] * wyv * wxv, bf2f(base[(unsigned)((yi * Wl + xi) * 256)]), acc);
            }
        }
    }
    acc += __shfl_xor(acc, 32);
    if (half == 0) sampled[(long)qg * 256 + h * 32 + c2] = acc;
}

// ---------------- K4: out = sampled @ W_out^T + b_out --------------------
__global__ __launch_bounds__(256) void k_out(
    const float* __restrict__ sampled, const float* __restrict__ Wout,
    const float* __restrict__ bout, float* __restrict__ out)
{
    __shared__ float slds[8][256];
    const int t = threadIdx.x;
    const int qg0 = blockIdx.x * 8;
    for (int idx = t; idx < 2048; idx += 256)
        ((float*)slds)[idx] = sampled[(long)qg0 * 256 + idx];
    __syncthreads();

    const float* wrow = Wout + (long)t * 256;
    float acc[8] = {0.f, 0.f, 0.f, 0.f, 0.f, 0.f, 0.f, 0.f};
    #pragma unroll 4
    for (int k4 = 0; k4 < 64; ++k4) {
        float4 w = *(const float4*)(wrow + k4 * 4);
        #pragma unroll
        for (int q = 0; q < 8; ++q) {
            float4 s = *(const float4*)&slds[q][k4 * 4];
            acc[q] += w.x * s.x + w.y * s.y + w.z * s.z + w.w * s.w;
        }
    }
    const float bias = bout[t];
    #pragma unroll
    for (int q = 0; q < 8; ++q)
        out[(long)(qg0 + q) * 256 + t] = acc[q] + bias;
}

extern "C" void kernel_launch(void* const* d_in, const int* in_sizes, int n_in,
                              void* d_out, int out_size, void* d_ws, size_t ws_size,
                              hipStream_t stream)
{
    const float* query = (const float*)d_in[0];
    const float* refp  = (const float*)d_in[1];
    const float* value = (const float*)d_in[2];
    const float* Woff  = (const float*)d_in[3];
    const float* boff  = (const float*)d_in[4];
    const float* Wattn = (const float*)d_in[5];
    const float* battn = (const float*)d_in[6];
    const float* Wval  = (const float*)d_in[7];
    const float* bval  = (const float*)d_in[8];
    const float* Wout  = (const float*)d_in[9];
    const float* bout  = (const float*)d_in[10];

    char* ws = (char*)d_ws;
    unsigned short* vbf = (unsigned short*)ws;                 // 69,632,000 B
    float* sampled = (float*)(ws + 69632000);                  //  4,915,200 B
    float* loc     = (float*)(ws + 69632000 + 4915200);        //  4,915,200 B
    float* aw      = (float*)(ws + 69632000 + 2 * 4915200);    //  2,457,600 B

    hipLaunchKernelGGL(k_val_gemm, dim3(2126), dim3(256), 0, stream,
                       value, Wval, bval, vbf);
    hipLaunchKernelGGL(k_offattn, dim3(600), dim3(384), 0, stream,
                       query, refp, Woff, boff, Wattn, battn, loc, aw);
    hipLaunchKernelGGL(k_sample, dim3(9600), dim3(256), 0, stream,
                       vbf, loc, aw, sampled);
    hipLaunchKernelGGL(k_out, dim3(600), dim3(256), 0, stream,
                       sampled, Wout, bout, (float*)d_out);
}

// Round 8
// 168.418 us; speedup vs baseline: 1.6266x; 1.6266x over previous
//
#include <hip/hip_runtime.h>
#include <hip/hip_bf16.h>

#define BS 16
#define LQ 300
#define DIM 256
#define NH 8
#define HD 32
#define SUMP 16
#define LV 8500
#define NQ (BS*LQ)       // 4800
#define MROWS (BS*LV)    // 136000
#define RS 40            // staging LDS row stride (shorts) = 80B (R3-proven)
#define ES 130           // epilogue C-tile row stride (shorts)

typedef __bf16 bf16x4 __attribute__((ext_vector_type(4)));
typedef __bf16 bf16x8 __attribute__((ext_vector_type(8)));
typedef float f32x4 __attribute__((ext_vector_type(4)));

__device__ __forceinline__ float bf2f(unsigned short u) {
    return __uint_as_float(((unsigned)u) << 16);
}
__device__ __forceinline__ bf16x4 cvt8B(float4 a) {
    bf16x4 r;
    r[0] = (__bf16)a.x; r[1] = (__bf16)a.y; r[2] = (__bf16)a.z; r[3] = (__bf16)a.w;
    return r;
}
__device__ __forceinline__ bf16x8 cvt16B(float4 a, float4 b) {
    bf16x8 r;
    r[0] = (__bf16)a.x; r[1] = (__bf16)a.y; r[2] = (__bf16)a.z; r[3] = (__bf16)a.w;
    r[4] = (__bf16)b.x; r[5] = (__bf16)b.y; r[6] = (__bf16)b.z; r[7] = (__bf16)b.w;
    return r;
}

// ---- K0: W_val -> bf16 k-panel wvb[k>>3][n] (makes B frags coalesced)
__global__ __launch_bounds__(256) void k_cvtB(
    const float* __restrict__ Wv, bf16x8* __restrict__ out)
{
    const int idx = blockIdx.x * 256 + threadIdx.x;   // 8192 = 32 kp x 256 n
    const int n = idx & 255, kp = idx >> 8;
    const float4 a0 = *(const float4*)(Wv + n * 256 + kp * 8);
    const float4 a1 = *(const float4*)(Wv + n * 256 + kp * 8 + 4);
    out[kp * 256 + n] = cvt16B(a0, a1);
}

// ---------------- K1: v_bf16 = bf16( value @ W_val^T + b_val ) -----------
// 128x128 tile, BK=32, 4 waves; dbuf LDS for A only (20KB); B frags loaded
// coalesced from the bf16 k-panel (L2-resident). R3-proven A staging +
// swapped-operand MFMA + LDS-staged bf16 epilogue.
__global__ __launch_bounds__(256, 4) void k_val_gemm(
    const float* __restrict__ value, const bf16x8* __restrict__ wvbp,
    const float* __restrict__ bv, unsigned short* __restrict__ vout)
{
    __shared__ unsigned short SH[10240];   // A0|A1 (5120 each) = 20KB; epilogue reuses 64*ES=8320
    unsigned short* const A0 = SH;
    unsigned short* const A1 = SH + 5120;

    const int t = threadIdx.x;
    const int lane = t & 63, wid = t >> 6;
    const int wm = (wid >> 1) * 64, wn = (wid & 1) * 64;
    const int fra = lane & 15;
    const int koff = (lane >> 4) * 8;

    // swizzle: the two bn-blocks of one bm are 8 ids apart (same XCD)
    const int id = blockIdx.x;               // 0..2125
    int bm, bn;
    if (id < 2112) { bm = (id >> 4) * 8 + (id & 7); bn = (id >> 3) & 1; }
    else           { int r = id - 2112; bm = 1056 + (r % 7); bn = r / 7; }

    f32x4 acc[4][4] = {};

    const int srow = t >> 3;           // 0..31
    const int scol = (t & 7) * 4;      // 0..28
    unsigned aoff[4];
    #pragma unroll
    for (int u = 0; u < 4; ++u) {
        long gr = (long)bm * 128 + u * 32 + srow;
        if (gr > MROWS - 1) gr = MROWS - 1;
        aoff[u] = (unsigned)(gr * 256 + scol);
    }
    const int lw = srow * RS + scol;

    {
        #pragma unroll
        for (int u = 0; u < 4; ++u) {
            float4 a = *(const float4*)(value + aoff[u]);
            *(bf16x4*)&A0[lw + u * 32 * RS] = cvt8B(a);
        }
    }
    __syncthreads();

    // FIX (R7 bug): B-fragment n-index must include bn*128
    const bf16x8* wvb_base = wvbp + bn * 128 + wn + fra + (lane >> 4) * 256;

#define STEP(Ac, An, KT)                                                       \
    {                                                                          \
        bf16x8 bfv[4];                                                         \
        _Pragma("unroll")                                                      \
        for (int j = 0; j < 4; ++j)                                            \
            bfv[j] = wvb_base[(KT) * 4 * 256 + j * 16];                        \
        float4 na[4];                                                          \
        if ((KT) < 7) {                                                        \
            const int k0 = ((KT) + 1) * 32;                                    \
            _Pragma("unroll")                                                  \
            for (int u = 0; u < 4; ++u)                                        \
                na[u] = *(const float4*)(value + aoff[u] + k0);                \
        }                                                                      \
        bf16x8 af[4];                                                          \
        _Pragma("unroll")                                                      \
        for (int i = 0; i < 4; ++i)                                            \
            af[i] = *(const bf16x8*)&Ac[(wm + i * 16 + fra) * RS + koff];      \
        _Pragma("unroll")                                                      \
        for (int i = 0; i < 4; ++i)                                            \
            _Pragma("unroll")                                                  \
            for (int j = 0; j < 4; ++j)                                        \
                acc[i][j] = __builtin_amdgcn_mfma_f32_16x16x32_bf16(           \
                    bfv[j], af[i], acc[i][j], 0, 0, 0);                        \
        if ((KT) < 7) {                                                        \
            _Pragma("unroll")                                                  \
            for (int u = 0; u < 4; ++u)                                        \
                *(bf16x4*)&An[lw + u * 32 * RS] = cvt8B(na[u]);                \
        }                                                                      \
        __syncthreads();                                                       \
    }

    STEP(A0, A1, 0)
    STEP(A1, A0, 1)
    STEP(A0, A1, 2)
    STEP(A1, A0, 3)
    STEP(A0, A1, 4)
    STEP(A1, A0, 5)
    STEP(A0, A1, 6)
    STEP(A1, A0, 7)
#undef STEP

    // epilogue: lane holds C[m][n0..n0+3]; 2 halves of 64 rows via LDS
    const int nreg = (lane >> 4) * 4;
    #pragma unroll
    for (int half = 0; half < 2; ++half) {
        __syncthreads();
        if ((wm >> 6) == half) {
            #pragma unroll
            for (int j = 0; j < 4; ++j) {
                const float4 bj = *(const float4*)&bv[bn * 128 + wn + j * 16 + nreg];
                #pragma unroll
                for (int i = 0; i < 4; ++i) {
                    const int mloc = i * 16 + fra;
                    const int n0 = wn + j * 16 + nreg;
                    float4 v;
                    v.x = acc[i][j][0] + bj.x;
                    v.y = acc[i][j][1] + bj.y;
                    v.z = acc[i][j][2] + bj.z;
                    v.w = acc[i][j][3] + bj.w;
                    *(bf16x4*)&SH[mloc * ES + n0] = cvt8B(v);
                }
            }
        }
        __syncthreads();
        #pragma unroll
        for (int u = 0; u < 4; ++u) {
            const int f = u * 256 + t;
            const int row = f >> 4;
            const int col = (f & 15) * 8;
            const long grow = (long)bm * 128 + half * 64 + row;
            if (grow < MROWS)
                *(uint4*)&vout[grow * 256 + bn * 128 + col] = *(const uint4*)&SH[row * ES + col];
        }
    }
}

// ---- shared staging+MFMA body for the small GEMMs (R3-proven skeleton) ----
#define GEMM_BODY(A_, W_, M_)                                                  \
    __shared__ unsigned short SH[20480];                                       \
    unsigned short* const A0 = SH;                                             \
    unsigned short* const A1 = SH + 5120;                                      \
    unsigned short* const B0 = SH + 10240;                                     \
    unsigned short* const B1 = SH + 15360;                                     \
    const int t = threadIdx.x;                                                 \
    const int bm = blockIdx.x, bn = blockIdx.y;                                \
    const int lane = t & 63, wid = t >> 6;                                     \
    const int wm = (wid >> 1) * 64, wn = (wid & 1) * 64;                       \
    const int fra = lane & 15;                                                 \
    const int koff = (lane >> 4) * 8;                                          \
    f32x4 acc[4][4] = {};                                                      \
    const int srow = t >> 3;                                                   \
    const int scol = (t & 7) * 4;                                              \
    unsigned aoff[4];                                                          \
    const float* pb0 = W_ + ((long)bn * 128 + srow) * 256 + scol;              \
    _Pragma("unroll")                                                          \
    for (int u = 0; u < 4; ++u) {                                              \
        long gr = (long)bm * 128 + u * 32 + srow;                              \
        if (gr > M_ - 1) gr = M_ - 1;                                          \
        aoff[u] = (unsigned)(gr * 256 + scol);                                 \
    }                                                                          \
    const int lw = srow * RS + scol;                                           \
    {                                                                          \
        _Pragma("unroll")                                                      \
        for (int u = 0; u < 4; ++u) {                                          \
            float4 a = *(const float4*)(A_ + aoff[u]);                         \
            float4 b = *(const float4*)(pb0 + u * 32 * 256);                   \
            *(bf16x4*)&A0[lw + u * 32 * RS] = cvt8B(a);                        \
            *(bf16x4*)&B0[lw + u * 32 * RS] = cvt8B(b);                        \
        }                                                                      \
    }                                                                          \
    __syncthreads();                                                           \
    _Pragma("unroll")                                                          \
    for (int kt = 0; kt < 8; ++kt) {                                           \
        unsigned short* Ac = (kt & 1) ? A1 : A0;                               \
        unsigned short* An = (kt & 1) ? A0 : A1;                               \
        unsigned short* Bc = (kt & 1) ? B1 : B0;                               \
        unsigned short* Bn = (kt & 1) ? B0 : B1;                               \
        float4 na[4], nb[4];                                                   \
        if (kt < 7) {                                                          \
            const int k0 = (kt + 1) * 32;                                      \
            _Pragma("unroll")                                                  \
            for (int u = 0; u < 4; ++u) {                                      \
                na[u] = *(const float4*)(A_ + aoff[u] + k0);                   \
                nb[u] = *(const float4*)(pb0 + u * 32 * 256 + k0);             \
            }                                                                  \
        }                                                                      \
        bf16x8 af[4], bfv[4];                                                  \
        _Pragma("unroll")                                                      \
        for (int i = 0; i < 4; ++i)                                            \
            af[i] = *(const bf16x8*)&Ac[(wm + i * 16 + fra) * RS + koff];      \
        _Pragma("unroll")                                                      \
        for (int j = 0; j < 4; ++j)                                            \
            bfv[j] = *(const bf16x8*)&Bc[(wn + j * 16 + fra) * RS + koff];     \
        _Pragma("unroll")                                                      \
        for (int i = 0; i < 4; ++i)                                            \
            _Pragma("unroll")                                                  \
            for (int j = 0; j < 4; ++j)                                        \
                acc[i][j] = __builtin_amdgcn_mfma_f32_16x16x32_bf16(           \
                    bfv[j], af[i], acc[i][j], 0, 0, 0);                        \
        if (kt < 7) {                                                          \
            _Pragma("unroll")                                                  \
            for (int u = 0; u < 4; ++u) {                                      \
                *(bf16x4*)&An[lw + u * 32 * RS] = cvt8B(na[u]);                \
                *(bf16x4*)&Bn[lw + u * 32 * RS] = cvt8B(nb[u]);                \
            }                                                                  \
        }                                                                      \
        __syncthreads();                                                       \
    }

// ---- K2a: attn logits = query @ W_attn^T + b (raw fp32, ldc=128) --------
__global__ __launch_bounds__(256) void k_gemm_attn(
    const float* __restrict__ A, const float* __restrict__ W,
    const float* __restrict__ bias, float* __restrict__ C)
{
    GEMM_BODY(A, W, NQ)
    const int nreg = (lane >> 4) * 4;
    #pragma unroll
    for (int j = 0; j < 4; ++j) {
        const int nn = wn + j * 16 + nreg;
        const float4 bj = *(const float4*)&bias[nn];
        #pragma unroll
        for (int i = 0; i < 4; ++i) {
            const long grow = (long)bm * 128 + wm + i * 16 + fra;
            if (grow < NQ) {
                float4 v;
                v.x = acc[i][j][0] + bj.x;
                v.y = acc[i][j][1] + bj.y;
                v.z = acc[i][j][2] + bj.z;
                v.w = acc[i][j][3] + bj.w;
                *(float4*)&C[grow * 128 + nn] = v;
            }
        }
    }
}

// ---- K2b: offsets GEMM with FUSED loc transform ------------------------
// col c = h*32 + p*2 + xy maps 1:1 to loc's flat layout; even c -> x, odd -> y
__global__ __launch_bounds__(256) void k_gemm_loc(
    const float* __restrict__ A, const float* __restrict__ W,
    const float* __restrict__ bias, const float* __restrict__ refp,
    float* __restrict__ loc)
{
    GEMM_BODY(A, W, NQ)
    const int nreg = (lane >> 4) * 4;
    float4 bj[4];
    #pragma unroll
    for (int j = 0; j < 4; ++j)
        bj[j] = *(const float4*)&bias[bn * 128 + wn + j * 16 + nreg];
    #pragma unroll
    for (int i = 0; i < 4; ++i) {
        const long grow = (long)bm * 128 + wm + i * 16 + fra;
        if (grow < NQ) {
            const float4 rp = *(const float4*)&refp[grow * 4];
            const float sx = 0.125f * rp.z, sy = 0.125f * rp.w;
            #pragma unroll
            for (int j = 0; j < 4; ++j) {
                float4 v;
                v.x = rp.x + (acc[i][j][0] + bj[j].x) * sx;
                v.y = rp.y + (acc[i][j][1] + bj[j].y) * sy;
                v.z = rp.x + (acc[i][j][2] + bj[j].z) * sx;
                v.w = rp.y + (acc[i][j][3] + bj[j].w) * sy;
                *(float4*)&loc[grow * 256 + bn * 128 + wn + j * 16 + nreg] = v;
            }
        }
    }
}

// ---- K2c: softmax over 16 points per (qg, h) ---------------------------
__global__ __launch_bounds__(256) void k_sm(
    const float* __restrict__ attnraw, float* __restrict__ aw)
{
    const int t = threadIdx.x;
    const int qg = blockIdx.x * 32 + (t >> 3);
    const int h = t & 7;
    const float* r = attnraw + (long)qg * 128 + h * 16;
    float a[16];
    #pragma unroll
    for (int u = 0; u < 4; ++u) {
        float4 v = *(const float4*)(r + u * 4);
        a[u*4+0] = v.x; a[u*4+1] = v.y; a[u*4+2] = v.z; a[u*4+3] = v.w;
    }
    float m = a[0];
    #pragma unroll
    for (int p = 1; p < 16; ++p) m = fmaxf(m, a[p]);
    float s = 0.f;
    #pragma unroll
    for (int p = 0; p < 16; ++p) { a[p] = expf(a[p] - m); s += a[p]; }
    const float inv = 1.f / s;
    float* ap = aw + (long)(qg * 8 + h) * 16;
    #pragma unroll
    for (int u = 0; u < 4; ++u) {
        float4 v;
        v.x = a[u*4+0] * inv; v.y = a[u*4+1] * inv;
        v.z = a[u*4+2] * inv; v.w = a[u*4+3] * inv;
        *(float4*)(ap + u * 4) = v;
    }
}

// ---------------- K3: bilinear sampling + attention-weighted sum ---------
__global__ __launch_bounds__(256) void k_sample(
    const unsigned short* __restrict__ vbf, const float* __restrict__ loc,
    const float* __restrict__ aw, float* __restrict__ sampled)
{
    const int t = threadIdx.x;
    const int wid = t >> 6, lane = t & 63;
    const int id = blockIdx.x * 4 + wid;   // qg*8 + h
    const int h = id & 7;
    const int qg = id >> 3;
    const int b = qg / LQ;
    const int c2 = lane & 31;
    const int half = lane >> 5;

    const unsigned short* vb = vbf + (long)b * LV * 256 + h * 32 + c2;
    const float* locp = loc + (long)id * SUMP * 2;
    const float* awp = aw + (long)id * SUMP;

    const int WLs[4] = {80, 40, 20, 10};
    const int SVs[4] = {0, 6400, 8000, 8400};

    float lx[8], ly[8], aww[8];
    #pragma unroll
    for (int pp = 0; pp < 8; ++pp) {
        const int p = pp * 2 + half;
        const float2 l2 = *(const float2*)&locp[p * 2];
        lx[pp] = l2.x; ly[pp] = l2.y;
        aww[pp] = awp[p];
    }

    float acc = 0.f;
    #pragma unroll
    for (int pp = 0; pp < 8; ++pp) {
        const int lvl = pp >> 1;
        const int Wl = WLs[lvl], Hl = WLs[lvl];
        const unsigned short* base = vb + SVs[lvl] * 256;
        const float x = lx[pp] * Wl - 0.5f, y = ly[pp] * Hl - 0.5f;
        const float x0f = floorf(x), y0f = floorf(y);
        const float wx = x - x0f, wy = y - y0f;
        const int x0 = (int)x0f, y0 = (int)y0f;
        #pragma unroll
        for (int dy = 0; dy < 2; ++dy) {
            const int yi = y0 + dy;
            if (yi < 0 || yi >= Hl) continue;
            const float wyv = dy ? wy : 1.f - wy;
            #pragma unroll
            for (int dx = 0; dx < 2; ++dx) {
                const int xi = x0 + dx;
                if (xi < 0 || xi >= Wl) continue;
                const float wxv = dx ? wx : 1.f - wx;
                acc = fmaf(aww[pp] * wyv * wxv, bf2f(base[(unsigned)((yi * Wl + xi) * 256)]), acc);
            }
        }
    }
    acc += __shfl_xor(acc, 32);
    if (half == 0) sampled[(long)qg * 256 + h * 32 + c2] = acc;
}

// ---------------- K4: out = sampled @ W_out^T + b_out (fp32, R5-proven) --
__global__ __launch_bounds__(256) void k_out(
    const float* __restrict__ sampled, const float* __restrict__ Wout,
    const float* __restrict__ bout, float* __restrict__ out)
{
    __shared__ float slds[8][256];
    const int t = threadIdx.x;
    const int qg0 = blockIdx.x * 8;
    for (int idx = t; idx < 2048; idx += 256)
        ((float*)slds)[idx] = sampled[(long)qg0 * 256 + idx];
    __syncthreads();

    const float* wrow = Wout + (long)t * 256;
    float acc[8] = {0.f, 0.f, 0.f, 0.f, 0.f, 0.f, 0.f, 0.f};
    #pragma unroll 4
    for (int k4 = 0; k4 < 64; ++k4) {
        float4 w = *(const float4*)(wrow + k4 * 4);
        #pragma unroll
        for (int q = 0; q < 8; ++q) {
            float4 s = *(const float4*)&slds[q][k4 * 4];
            acc[q] += w.x * s.x + w.y * s.y + w.z * s.z + w.w * s.w;
        }
    }
    const float bias = bout[t];
    #pragma unroll
    for (int q = 0; q < 8; ++q)
        out[(long)(qg0 + q) * 256 + t] = acc[q] + bias;
}

extern "C" void kernel_launch(void* const* d_in, const int* in_sizes, int n_in,
                              void* d_out, int out_size, void* d_ws, size_t ws_size,
                              hipStream_t stream)
{
    const float* query = (const float*)d_in[0];
    const float* refp  = (const float*)d_in[1];
    const float* value = (const float*)d_in[2];
    const float* Woff  = (const float*)d_in[3];
    const float* boff  = (const float*)d_in[4];
    const float* Wattn = (const float*)d_in[5];
    const float* battn = (const float*)d_in[6];
    const float* Wval  = (const float*)d_in[7];
    const float* bval  = (const float*)d_in[8];
    const float* Wout  = (const float*)d_in[9];
    const float* bout  = (const float*)d_in[10];

    // total footprint = 81,920,000 B (== proven-safe R1-R5 footprint)
    char* ws = (char*)d_ws;
    unsigned short* vbf = (unsigned short*)ws;                 // [0, 69,632,000)
    float* loc     = (float*)(ws + 69632000);                  // 4,915,200
    float* aw      = (float*)(ws + 74547200);                  // 2,457,600
    float* attnraw = (float*)(ws + 77004800);                  // 2,457,600 (dead after k_sm)
    bf16x8* wvb    = (bf16x8*)(ws + 79462400);                 //   131,072 (dead after k_val_gemm)
    float* sampled = (float*)(ws + 77004800);                  // 4,915,200 (aliases attnraw+wvb, written later)

    hipLaunchKernelGGL(k_cvtB, dim3(32), dim3(256), 0, stream, Wval, wvb);
    hipLaunchKernelGGL(k_val_gemm, dim3(2126), dim3(256), 0, stream,
                       value, wvb, bval, vbf);
    hipLaunchKernelGGL(k_gemm_loc, dim3(38, 2), dim3(256), 0, stream,
                       query, Woff, boff, refp, loc);
    hipLaunchKernelGGL(k_gemm_attn, dim3(38, 1), dim3(256), 0, stream,
                       query, Wattn, battn, attnraw);
    hipLaunchKernelGGL(k_sm, dim3(150), dim3(256), 0, stream, attnraw, aw);
    hipLaunchKernelGGL(k_sample, dim3(9600), dim3(256), 0, stream,
                       vbf, loc, aw, sampled);
    hipLaunchKernelGGL(k_out, dim3(600), dim3(256), 0, stream,
                       sampled, Wout, bout, (float*)d_out);
}

// Round 9
// 130.024 us; speedup vs baseline: 2.1069x; 1.2953x over previous
//
#include <hip/hip_runtime.h>
#include <hip/hip_bf16.h>

#define BS 16
#define LQ 300
#define DIM 256
#define NH 8
#define HD 32
#define SUMP 16
#define LV 8500
#define NQ (BS*LQ)       // 4800
#define MROWS (BS*LV)    // 136000
#define RS 40            // staging LDS row stride (shorts) = 80B (R3-proven)
#define ES 130           // epilogue C-tile row stride (shorts)

typedef __bf16 bf16x4 __attribute__((ext_vector_type(4)));
typedef __bf16 bf16x8 __attribute__((ext_vector_type(8)));
typedef float f32x4 __attribute__((ext_vector_type(4)));

__device__ __forceinline__ float bf2f(unsigned short u) {
    return __uint_as_float(((unsigned)u) << 16);
}
__device__ __forceinline__ bf16x4 cvt8B(float4 a) {
    bf16x4 r;
    r[0] = (__bf16)a.x; r[1] = (__bf16)a.y; r[2] = (__bf16)a.z; r[3] = (__bf16)a.w;
    return r;
}
__device__ __forceinline__ bf16x8 cvt16B(float4 a, float4 b) {
    bf16x8 r;
    r[0] = (__bf16)a.x; r[1] = (__bf16)a.y; r[2] = (__bf16)a.z; r[3] = (__bf16)a.w;
    r[4] = (__bf16)b.x; r[5] = (__bf16)b.y; r[6] = (__bf16)b.z; r[7] = (__bf16)b.w;
    return r;
}

// ---- K0: W_val -> bf16 k-panel wvb[k>>3][n] (makes B frags coalesced)
__global__ __launch_bounds__(256) void k_cvtB(
    const float* __restrict__ Wv, bf16x8* __restrict__ out)
{
    const int idx = blockIdx.x * 256 + threadIdx.x;   // 8192 = 32 kp x 256 n
    const int n = idx & 255, kp = idx >> 8;
    const float4 a0 = *(const float4*)(Wv + n * 256 + kp * 8);
    const float4 a1 = *(const float4*)(Wv + n * 256 + kp * 8 + 4);
    out[kp * 256 + n] = cvt16B(a0, a1);
}

// ---------------- K1: v_bf16 = bf16( value @ W_val^T + b_val ) -----------
// (unchanged from R8 — passing, structure proven)
__global__ __launch_bounds__(256, 4) void k_val_gemm(
    const float* __restrict__ value, const bf16x8* __restrict__ wvbp,
    const float* __restrict__ bv, unsigned short* __restrict__ vout)
{
    __shared__ unsigned short SH[10240];   // A0|A1 (5120 each) = 20KB; epilogue reuses 64*ES
    unsigned short* const A0 = SH;
    unsigned short* const A1 = SH + 5120;

    const int t = threadIdx.x;
    const int lane = t & 63, wid = t >> 6;
    const int wm = (wid >> 1) * 64, wn = (wid & 1) * 64;
    const int fra = lane & 15;
    const int koff = (lane >> 4) * 8;

    const int id = blockIdx.x;               // 0..2125
    int bm, bn;
    if (id < 2112) { bm = (id >> 4) * 8 + (id & 7); bn = (id >> 3) & 1; }
    else           { int r = id - 2112; bm = 1056 + (r % 7); bn = r / 7; }

    f32x4 acc[4][4] = {};

    const int srow = t >> 3;           // 0..31
    const int scol = (t & 7) * 4;      // 0..28
    unsigned aoff[4];
    #pragma unroll
    for (int u = 0; u < 4; ++u) {
        long gr = (long)bm * 128 + u * 32 + srow;
        if (gr > MROWS - 1) gr = MROWS - 1;
        aoff[u] = (unsigned)(gr * 256 + scol);
    }
    const int lw = srow * RS + scol;

    {
        #pragma unroll
        for (int u = 0; u < 4; ++u) {
            float4 a = *(const float4*)(value + aoff[u]);
            *(bf16x4*)&A0[lw + u * 32 * RS] = cvt8B(a);
        }
    }
    __syncthreads();

    const bf16x8* wvb_base = wvbp + bn * 128 + wn + fra + (lane >> 4) * 256;

#define STEP(Ac, An, KT)                                                       \
    {                                                                          \
        bf16x8 bfv[4];                                                         \
        _Pragma("unroll")                                                      \
        for (int j = 0; j < 4; ++j)                                            \
            bfv[j] = wvb_base[(KT) * 4 * 256 + j * 16];                        \
        float4 na[4];                                                          \
        if ((KT) < 7) {                                                        \
            const int k0 = ((KT) + 1) * 32;                                    \
            _Pragma("unroll")                                                  \
            for (int u = 0; u < 4; ++u)                                        \
                na[u] = *(const float4*)(value + aoff[u] + k0);                \
        }                                                                      \
        bf16x8 af[4];                                                          \
        _Pragma("unroll")                                                      \
        for (int i = 0; i < 4; ++i)                                            \
            af[i] = *(const bf16x8*)&Ac[(wm + i * 16 + fra) * RS + koff];      \
        _Pragma("unroll")                                                      \
        for (int i = 0; i < 4; ++i)                                            \
            _Pragma("unroll")                                                  \
            for (int j = 0; j < 4; ++j)                                        \
                acc[i][j] = __builtin_amdgcn_mfma_f32_16x16x32_bf16(           \
                    bfv[j], af[i], acc[i][j], 0, 0, 0);                        \
        if ((KT) < 7) {                                                        \
            _Pragma("unroll")                                                  \
            for (int u = 0; u < 4; ++u)                                        \
                *(bf16x4*)&An[lw + u * 32 * RS] = cvt8B(na[u]);                \
        }                                                                      \
        __syncthreads();                                                       \
    }

    STEP(A0, A1, 0)
    STEP(A1, A0, 1)
    STEP(A0, A1, 2)
    STEP(A1, A0, 3)
    STEP(A0, A1, 4)
    STEP(A1, A0, 5)
    STEP(A0, A1, 6)
    STEP(A1, A0, 7)
#undef STEP

    const int nreg = (lane >> 4) * 4;
    #pragma unroll
    for (int half = 0; half < 2; ++half) {
        __syncthreads();
        if ((wm >> 6) == half) {
            #pragma unroll
            for (int j = 0; j < 4; ++j) {
                const float4 bj = *(const float4*)&bv[bn * 128 + wn + j * 16 + nreg];
                #pragma unroll
                for (int i = 0; i < 4; ++i) {
                    const int mloc = i * 16 + fra;
                    const int n0 = wn + j * 16 + nreg;
                    float4 v;
                    v.x = acc[i][j][0] + bj.x;
                    v.y = acc[i][j][1] + bj.y;
                    v.z = acc[i][j][2] + bj.z;
                    v.w = acc[i][j][3] + bj.w;
                    *(bf16x4*)&SH[mloc * ES + n0] = cvt8B(v);
                }
            }
        }
        __syncthreads();
        #pragma unroll
        for (int u = 0; u < 4; ++u) {
            const int f = u * 256 + t;
            const int row = f >> 4;
            const int col = (f & 15) * 8;
            const long grow = (long)bm * 128 + half * 64 + row;
            if (grow < MROWS)
                *(uint4*)&vout[grow * 256 + bn * 128 + col] = *(const uint4*)&SH[row * ES + col];
        }
    }
}

// ---- shared staging+MFMA body for the small GEMMs (R3-proven skeleton) ----
#define GEMM_BODY(A_, W_, M_)                                                  \
    __shared__ unsigned short SH[20480];                                       \
    unsigned short* const A0 = SH;                                             \
    unsigned short* const A1 = SH + 5120;                                      \
    unsigned short* const B0 = SH + 10240;                                     \
    unsigned short* const B1 = SH + 15360;                                     \
    const int t = threadIdx.x;                                                 \
    const int bm = blockIdx.x, bn = blockIdx.y;                                \
    const int lane = t & 63, wid = t >> 6;                                     \
    const int wm = (wid >> 1) * 64, wn = (wid & 1) * 64;                       \
    const int fra = lane & 15;                                                 \
    const int koff = (lane >> 4) * 8;                                          \
    f32x4 acc[4][4] = {};                                                      \
    const int srow = t >> 3;                                                   \
    const int scol = (t & 7) * 4;                                              \
    unsigned aoff[4];                                                          \
    const float* pb0 = W_ + ((long)bn * 128 + srow) * 256 + scol;              \
    _Pragma("unroll")                                                          \
    for (int u = 0; u < 4; ++u) {                                              \
        long gr = (long)bm * 128 + u * 32 + srow;                              \
        if (gr > M_ - 1) gr = M_ - 1;                                          \
        aoff[u] = (unsigned)(gr * 256 + scol);                                 \
    }                                                                          \
    const int lw = srow * RS + scol;                                           \
    {                                                                          \
        _Pragma("unroll")                                                      \
        for (int u = 0; u < 4; ++u) {                                          \
            float4 a = *(const float4*)(A_ + aoff[u]);                         \
            float4 b = *(const float4*)(pb0 + u * 32 * 256);                   \
            *(bf16x4*)&A0[lw + u * 32 * RS] = cvt8B(a);                        \
            *(bf16x4*)&B0[lw + u * 32 * RS] = cvt8B(b);                        \
        }                                                                      \
    }                                                                          \
    __syncthreads();                                                           \
    _Pragma("unroll")                                                          \
    for (int kt = 0; kt < 8; ++kt) {                                           \
        unsigned short* Ac = (kt & 1) ? A1 : A0;                               \
        unsigned short* An = (kt & 1) ? A0 : A1;                               \
        unsigned short* Bc = (kt & 1) ? B1 : B0;                               \
        unsigned short* Bn = (kt & 1) ? B0 : B1;                               \
        float4 na[4], nb[4];                                                   \
        if (kt < 7) {                                                          \
            const int k0 = (kt + 1) * 32;                                      \
            _Pragma("unroll")                                                  \
            for (int u = 0; u < 4; ++u) {                                      \
                na[u] = *(const float4*)(A_ + aoff[u] + k0);                   \
                nb[u] = *(const float4*)(pb0 + u * 32 * 256 + k0);             \
            }                                                                  \
        }                                                                      \
        bf16x8 af[4], bfv[4];                                                  \
        _Pragma("unroll")                                                      \
        for (int i = 0; i < 4; ++i)                                            \
            af[i] = *(const bf16x8*)&Ac[(wm + i * 16 + fra) * RS + koff];      \
        _Pragma("unroll")                                                      \
        for (int j = 0; j < 4; ++j)                                            \
            bfv[j] = *(const bf16x8*)&Bc[(wn + j * 16 + fra) * RS + koff];     \
        _Pragma("unroll")                                                      \
        for (int i = 0; i < 4; ++i)                                            \
            _Pragma("unroll")                                                  \
            for (int j = 0; j < 4; ++j)                                        \
                acc[i][j] = __builtin_amdgcn_mfma_f32_16x16x32_bf16(           \
                    bfv[j], af[i], acc[i][j], 0, 0, 0);                        \
        if (kt < 7) {                                                          \
            _Pragma("unroll")                                                  \
            for (int u = 0; u < 4; ++u) {                                      \
                *(bf16x4*)&An[lw + u * 32 * RS] = cvt8B(na[u]);                \
                *(bf16x4*)&Bn[lw + u * 32 * RS] = cvt8B(nb[u]);                \
            }                                                                  \
        }                                                                      \
        __syncthreads();                                                       \
    }

// ---- K2a: attn logits GEMM with FUSED softmax -> aw --------------------
// For fixed (i,j) the 16 logits of one (row, h) group live in the 4 lanes
// {same fra, lane>>4 = 0..3}; butterfly shfl_xor(16/32) gives max and sum.
__global__ __launch_bounds__(256) void k_gemm_attn(
    const float* __restrict__ A, const float* __restrict__ W,
    const float* __restrict__ bias, float* __restrict__ awout)
{
    GEMM_BODY(A, W, NQ)
    const int nreg = (lane >> 4) * 4;
    #pragma unroll
    for (int i = 0; i < 4; ++i) {
        const long grow = (long)bm * 128 + wm + i * 16 + fra;
        #pragma unroll
        for (int j = 0; j < 4; ++j) {
            const int n0 = wn + j * 16 + nreg;
            const float4 bj = *(const float4*)&bias[n0];
            float vx = acc[i][j][0] + bj.x;
            float vy = acc[i][j][1] + bj.y;
            float vz = acc[i][j][2] + bj.z;
            float vw = acc[i][j][3] + bj.w;
            float mx = fmaxf(fmaxf(vx, vy), fmaxf(vz, vw));
            mx = fmaxf(mx, __shfl_xor(mx, 16));
            mx = fmaxf(mx, __shfl_xor(mx, 32));
            float ex = expf(vx - mx), ey = expf(vy - mx);
            float ez = expf(vz - mx), ew = expf(vw - mx);
            float s = ex + ey + ez + ew;
            s += __shfl_xor(s, 16);
            s += __shfl_xor(s, 32);
            const float inv = 1.f / s;
            if (grow < NQ) {
                const int hh = (wn >> 4) + j;
                float4 o;
                o.x = ex * inv; o.y = ey * inv; o.z = ez * inv; o.w = ew * inv;
                *(float4*)&awout[(grow * 8 + hh) * 16 + nreg] = o;
            }
        }
    }
}

// ---- K2b: offsets GEMM with FUSED loc transform (R8-proven) ------------
__global__ __launch_bounds__(256) void k_gemm_loc(
    const float* __restrict__ A, const float* __restrict__ W,
    const float* __restrict__ bias, const float* __restrict__ refp,
    float* __restrict__ loc)
{
    GEMM_BODY(A, W, NQ)
    const int nreg = (lane >> 4) * 4;
    float4 bj[4];
    #pragma unroll
    for (int j = 0; j < 4; ++j)
        bj[j] = *(const float4*)&bias[bn * 128 + wn + j * 16 + nreg];
    #pragma unroll
    for (int i = 0; i < 4; ++i) {
        const long grow = (long)bm * 128 + wm + i * 16 + fra;
        if (grow < NQ) {
            const float4 rp = *(const float4*)&refp[grow * 4];
            const float sx = 0.125f * rp.z, sy = 0.125f * rp.w;
            #pragma unroll
            for (int j = 0; j < 4; ++j) {
                float4 v;
                v.x = rp.x + (acc[i][j][0] + bj[j].x) * sx;
                v.y = rp.y + (acc[i][j][1] + bj[j].y) * sy;
                v.z = rp.x + (acc[i][j][2] + bj[j].z) * sx;
                v.w = rp.y + (acc[i][j][3] + bj[j].w) * sy;
                *(float4*)&loc[grow * 256 + bn * 128 + wn + j * 16 + nreg] = v;
            }
        }
    }
}

// ---- K4: out = sampled @ W_out^T + b_out (MFMA, fp32 direct stores) ----
__global__ __launch_bounds__(256) void k_gemm_out(
    const float* __restrict__ A, const float* __restrict__ W,
    const float* __restrict__ bias, float* __restrict__ out)
{
    GEMM_BODY(A, W, NQ)
    const int nreg = (lane >> 4) * 4;
    #pragma unroll
    for (int j = 0; j < 4; ++j) {
        const int nn = bn * 128 + wn + j * 16 + nreg;
        const float4 bj = *(const float4*)&bias[nn];
        #pragma unroll
        for (int i = 0; i < 4; ++i) {
            const long grow = (long)bm * 128 + wm + i * 16 + fra;
            if (grow < NQ) {
                float4 v;
                v.x = acc[i][j][0] + bj.x;
                v.y = acc[i][j][1] + bj.y;
                v.z = acc[i][j][2] + bj.z;
                v.w = acc[i][j][3] + bj.w;
                *(float4*)&out[grow * 256 + nn] = v;
            }
        }
    }
}

// ---------------- K3: bilinear sampling + attention-weighted sum ---------
// Wave = one (qg,h). Lane = (channel-pair cp = lane&15, level q = lane>>4).
// Each lane gathers uint (2 bf16 channels) for its level's 4 points:
// 16 VMEM instrs/lane (was 32), same 64 line-touches/wave. Level-sum via
// shfl_xor(16/32); lanes q==0 store float2 (coalesced 128B per group).
__global__ __launch_bounds__(256) void k_sample(
    const unsigned short* __restrict__ vbf, const float* __restrict__ loc,
    const float* __restrict__ aw, float* __restrict__ sampled)
{
    const int t = threadIdx.x;
    const int wid = t >> 6, lane = t & 63;
    const int id = blockIdx.x * 4 + wid;   // qg*8 + h
    const int h = id & 7;
    const int qg = id >> 3;
    const int b = qg / LQ;
    const int cp = lane & 15;              // channels 2cp, 2cp+1
    const int q = lane >> 4;               // level 0..3

    const int WLs[4] = {80, 40, 20, 10};
    const int SVs[4] = {0, 6400, 8000, 8400};
    const int Wl = WLs[q];
    const unsigned short* vb = vbf + (long)b * LV * 256 + (long)SVs[q] * 256 + h * 32 + cp * 2;

    const float* locp = loc + (long)id * 32 + q * 8;   // this level's 4 pts x 2
    const float* awp  = aw  + (long)id * 16 + q * 4;

    const float4 l01 = *(const float4*)locp;
    const float4 l23 = *(const float4*)(locp + 4);
    const float4 aw4 = *(const float4*)awp;
    const float lx[4] = {l01.x, l01.z, l23.x, l23.z};
    const float ly[4] = {l01.y, l01.w, l23.y, l23.w};
    const float awv[4] = {aw4.x, aw4.y, aw4.z, aw4.w};

    float ax = 0.f, ay = 0.f;
    #pragma unroll
    for (int k = 0; k < 4; ++k) {
        const float x = lx[k] * Wl - 0.5f, y = ly[k] * Wl - 0.5f;
        const float x0f = floorf(x), y0f = floorf(y);
        const float wx = x - x0f, wy = y - y0f;
        const int x0 = (int)x0f, y0 = (int)y0f;
        #pragma unroll
        for (int dy = 0; dy < 2; ++dy) {
            const int yi = y0 + dy;
            if (yi < 0 || yi >= Wl) continue;
            const float wyv = dy ? wy : 1.f - wy;
            #pragma unroll
            for (int dx = 0; dx < 2; ++dx) {
                const int xi = x0 + dx;
                if (xi < 0 || xi >= Wl) continue;
                const float w = awv[k] * wyv * (dx ? wx : 1.f - wx);
                const unsigned uu = *(const unsigned*)&vb[(unsigned)((yi * Wl + xi) * 256)];
                ax = fmaf(w, __uint_as_float((uu & 0xffffu) << 16), ax);
                ay = fmaf(w, __uint_as_float(uu & 0xffff0000u), ay);
            }
        }
    }
    ax += __shfl_xor(ax, 16); ay += __shfl_xor(ay, 16);
    ax += __shfl_xor(ax, 32); ay += __shfl_xor(ay, 32);
    if (q == 0) {
        float2 o; o.x = ax; o.y = ay;
        *(float2*)&sampled[(long)qg * 256 + h * 32 + cp * 2] = o;
    }
}

extern "C" void kernel_launch(void* const* d_in, const int* in_sizes, int n_in,
                              void* d_out, int out_size, void* d_ws, size_t ws_size,
                              hipStream_t stream)
{
    const float* query = (const float*)d_in[0];
    const float* refp  = (const float*)d_in[1];
    const float* value = (const float*)d_in[2];
    const float* Woff  = (const float*)d_in[3];
    const float* boff  = (const float*)d_in[4];
    const float* Wattn = (const float*)d_in[5];
    const float* battn = (const float*)d_in[6];
    const float* Wval  = (const float*)d_in[7];
    const float* bval  = (const float*)d_in[8];
    const float* Wout  = (const float*)d_in[9];
    const float* bout  = (const float*)d_in[10];

    // total footprint = 81,920,000 B (proven-safe)
    char* ws = (char*)d_ws;
    unsigned short* vbf = (unsigned short*)ws;                 // [0, 69,632,000)
    float* loc     = (float*)(ws + 69632000);                  // 4,915,200
    float* aw      = (float*)(ws + 74547200);                  // 2,457,600
    bf16x8* wvb    = (bf16x8*)(ws + 77004800);                 //   131,072 (dead after k_val_gemm)
    float* sampled = (float*)(ws + 77004800);                  // 4,915,200 (aliases wvb, written later)

    hipLaunchKernelGGL(k_cvtB, dim3(32), dim3(256), 0, stream, Wval, wvb);
    hipLaunchKernelGGL(k_val_gemm, dim3(2126), dim3(256), 0, stream,
                       value, wvb, bval, vbf);
    hipLaunchKernelGGL(k_gemm_loc, dim3(38, 2), dim3(256), 0, stream,
                       query, Woff, boff, refp, loc);
    hipLaunchKernelGGL(k_gemm_attn, dim3(38, 1), dim3(256), 0, stream,
                       query, Wattn, battn, aw);
    hipLaunchKernelGGL(k_sample, dim3(9600), dim3(256), 0, stream,
                       vbf, loc, aw, sampled);
    hipLaunchKernelGGL(k_gemm_out, dim3(38, 2), dim3(256), 0, stream,
                       sampled, Wout, bout, (float*)d_out);
}